// Round 1
// baseline (353.595 us; speedup 1.0000x reference)
//
#include <hip/hip_runtime.h>
#include <math.h>

// Problem constants
#define NROWS 32768          // 32*32*32 rows (b,h,w)
#define NE    1024           // embeddings
#define CDIM  256            // embedding dim
#define ZB_STRIDE 262144     // 256*1024 floats per batch in z (b,c,h,w layout)

// Output layout (flat float32, concatenated in reference return order)
#define ZQ_OFF   0                  // 8388608
#define LOSS_OFF 8388608            // 1
#define PERP_OFF 8388609            // 1
#define ENC_OFF  8388610            // 33554432
#define IDX_OFF  41943042           // 32768 (indices stored as float)

// ---------------------------------------------------------------------------
// numpy-pairwise-exact sum of squares over 256 elements with compile-time
// stride. Mirrors numpy pairwise_sum: split 128+128, each via 8 accumulators
// then ((r0+r1)+(r2+r3))+((r4+r5)+(r6+r7)). __fmul_rn/__fadd_rn block
// fp-contraction so rounding matches np exactly.
template<int STRIDE>
__device__ __forceinline__ float np_sumsq_256(const float* __restrict__ base) {
  float tot[2];
#pragma unroll
  for (int hh = 0; hh < 2; ++hh) {
    float r[8];
#pragma unroll
    for (int j = 0; j < 8; ++j) {
      float x = base[(size_t)(hh * 128 + j) * STRIDE];
      r[j] = __fmul_rn(x, x);
    }
    for (int i = 8; i < 128; i += 8) {
#pragma unroll
      for (int j = 0; j < 8; ++j) {
        float x = base[(size_t)(hh * 128 + i + j) * STRIDE];
        r[j] = __fadd_rn(r[j], __fmul_rn(x, x));
      }
    }
    tot[hh] = __fadd_rn(__fadd_rn(__fadd_rn(r[0], r[1]), __fadd_rn(r[2], r[3])),
                        __fadd_rn(__fadd_rn(r[4], r[5]), __fadd_rn(r[6], r[7])));
  }
  return __fadd_rn(tot[0], tot[1]);
}

// znorm[n] = sum_c z[b,c,h,w]^2, n = b*1024 + h*32 + w.
// Consecutive n -> consecutive addresses for fixed c => coalesced.
__global__ __launch_bounds__(256) void znorm_kernel(const float* __restrict__ z,
                                                    float* __restrict__ znorm) {
  int n = blockIdx.x * 256 + threadIdx.x;
  const float* base = z + (size_t)(n >> 10) * ZB_STRIDE + (n & 1023);
  znorm[n] = np_sumsq_256<1024>(base);
}

__global__ __launch_bounds__(256) void enorm_kernel(const float* __restrict__ emb,
                                                    float* __restrict__ enorm) {
  int n = blockIdx.x * 256 + threadIdx.x;  // < 1024
  const float* base = emb + (size_t)n * CDIM;
  enorm[n] = np_sumsq_256<1>(base);
}

// ---------------------------------------------------------------------------
// Main kernel: tiled fp32 "GEMM" computing dot(z_row, emb_e) for a 64-row
// block against all 1024 embeddings, fused running argmin of
// d = (znorm + enorm) - 2*dot with first-index tie-breaking.
#define BM 64
#define BN 64
#define BK 16

__global__ __launch_bounds__(256) void argmin_kernel(const float* __restrict__ z,
                                                     const float* __restrict__ emb,
                                                     const float* __restrict__ enorm,
                                                     const float* __restrict__ znorm,
                                                     int* __restrict__ idx_out) {
  __shared__ float As[BK][BM + 4];  // stride 68 floats = 272B (16B aligned rows)
  __shared__ float Bs[BK][BN + 4];
  __shared__ float red_d[16][BM];
  __shared__ int   red_i[16][BM];

  const int tid = threadIdx.x;
  const int tx = tid & 15;   // embedding-tile dim
  const int ty = tid >> 4;   // row-tile dim
  const int n0 = blockIdx.x * BM;
  // rows n0..n0+63 are contiguous in memory for fixed c (64 | 1024)
  const float* zbase = z + (size_t)(n0 >> 10) * ZB_STRIDE + (n0 & 1023);

  const int lr = tid & 63;   // load row
  const int lk = tid >> 6;   // load k-group (0..3)

  float zn[4];
#pragma unroll
  for (int i = 0; i < 4; ++i) zn[i] = znorm[n0 + ty * 4 + i];

  float bestd[4];
  int   besti[4];
#pragma unroll
  for (int i = 0; i < 4; ++i) { bestd[i] = 3.402823466e+38f; besti[i] = 0; }

  for (int e0 = 0; e0 < NE; e0 += BN) {
    float acc[4][4] = {};
    for (int kt = 0; kt < CDIM; kt += BK) {
      // stage A: 64 rows x 16 k (coalesced: 64 consecutive floats per k)
#pragma unroll
      for (int u = 0; u < 4; ++u) {
        int k = lk + 4 * u;
        As[k][lr] = zbase[(size_t)(kt + k) * 1024 + lr];
      }
      // stage B: 64 emb x 16 k, float4 from row-major emb, transposed store
      {
        int e = tid >> 2;           // 0..63
        int kq = (tid & 3) * 4;     // 0,4,8,12
        const float4 v = *reinterpret_cast<const float4*>(
            &emb[(size_t)(e0 + e) * CDIM + kt + kq]);
        Bs[kq + 0][e] = v.x;
        Bs[kq + 1][e] = v.y;
        Bs[kq + 2][e] = v.z;
        Bs[kq + 3][e] = v.w;
      }
      __syncthreads();
#pragma unroll
      for (int k = 0; k < BK; ++k) {
        const float4 av = *reinterpret_cast<const float4*>(&As[k][ty * 4]);
        const float4 bv = *reinterpret_cast<const float4*>(&Bs[k][tx * 4]);
        const float aa[4] = {av.x, av.y, av.z, av.w};
        const float bb[4] = {bv.x, bv.y, bv.z, bv.w};
#pragma unroll
        for (int i = 0; i < 4; ++i)
#pragma unroll
          for (int j = 0; j < 4; ++j)
            acc[i][j] = fmaf(aa[i], bb[j], acc[i][j]);
      }
      __syncthreads();
    }
    // epilogue: d = (znorm + enorm) - 2*dot, running min (e ascending)
#pragma unroll
    for (int j = 0; j < 4; ++j) {
      int e = e0 + tx * 4 + j;
      float en = enorm[e];
#pragma unroll
      for (int i = 0; i < 4; ++i) {
        float s = __fadd_rn(zn[i], en);
        float d = __fsub_rn(s, __fmul_rn(2.0f, acc[i][j]));
        if (d < bestd[i]) { bestd[i] = d; besti[i] = e; }
      }
    }
  }

  // cross-thread (tx) reduction with (d, idx) lexicographic order
#pragma unroll
  for (int i = 0; i < 4; ++i) {
    red_d[tx][ty * 4 + i] = bestd[i];
    red_i[tx][ty * 4 + i] = besti[i];
  }
  __syncthreads();
  if (tid < 64) {
    float bd = red_d[0][tid];
    int   bi = red_i[0][tid];
#pragma unroll
    for (int t = 1; t < 16; ++t) {
      float d = red_d[t][tid];
      int   ii = red_i[t][tid];
      if (d < bd || (d == bd && ii < bi)) { bd = d; bi = ii; }
    }
    idx_out[n0 + tid] = bi;
  }
}

// ---------------------------------------------------------------------------
// one-hot scatter + index-as-float + int histogram
__global__ __launch_bounds__(256) void scatter_kernel(const int* __restrict__ idx,
                                                      float* __restrict__ out_enc,
                                                      float* __restrict__ out_idxf,
                                                      int* __restrict__ hist) {
  int n = blockIdx.x * 256 + threadIdx.x;
  int e = idx[n];
  out_enc[(size_t)n * NE + e] = 1.0f;
  out_idxf[n] = (float)e;
  atomicAdd(&hist[e], 1);
}

// gather z_q (written in (b,c,h,w) layout) + per-block loss partial sums
__global__ __launch_bounds__(256) void gather_kernel(const float* __restrict__ z,
                                                     const float* __restrict__ emb,
                                                     const int* __restrict__ idx,
                                                     float* __restrict__ zq_out,
                                                     float* __restrict__ loss_part) {
  int bh = blockIdx.x;            // b*32 + h
  int b = bh >> 5, h = bh & 31;
  int t = threadIdx.x;
  int w = t & 31;
  int g = t >> 5;                 // 0..7 -> c chunk
  int n = b * 1024 + h * 32 + w;
  int e = idx[n];
  const float* zb = z + (size_t)b * ZB_STRIDE + h * 32 + w;
  const float* eb = emb + (size_t)e * CDIM;
  float* ob = zq_out + (size_t)b * ZB_STRIDE + h * 32 + w;
  float lsum = 0.f;
#pragma unroll
  for (int u = 0; u < 32; ++u) {
    int c = g * 32 + u;
    float q = eb[c];
    float x = zb[(size_t)c * 1024];
    ob[(size_t)c * 1024] = q;
    float dd = q - x;
    lsum = fmaf(dd, dd, lsum);
  }
  __shared__ float red[256];
  red[t] = lsum;
  __syncthreads();
  for (int s2 = 128; s2 > 0; s2 >>= 1) {
    if (t < s2) red[t] += red[t + s2];
    __syncthreads();
  }
  if (t == 0) loss_part[bh] = red[0];
}

// deterministic finalize: loss from 1024 fixed partials; perplexity from hist
__global__ __launch_bounds__(256) void finalize_kernel(const float* __restrict__ loss_part,
                                                       const int* __restrict__ hist,
                                                       float* __restrict__ out_loss,
                                                       float* __restrict__ out_perp) {
  __shared__ float red[256];
  int t = threadIdx.x;
  float s = 0.f;
  for (int i = t; i < 1024; i += 256) s += loss_part[i];
  red[t] = s;
  __syncthreads();
  for (int s2 = 128; s2 > 0; s2 >>= 1) {
    if (t < s2) red[t] += red[t + s2];
    __syncthreads();
  }
  if (t == 0) {
    float m = red[0] / 8388608.0f;
    out_loss[0] = __fadd_rn(m, 0.25f * m);
  }
  __syncthreads();
  float hs = 0.f;
  for (int i = t; i < 1024; i += 256) {
    float em = (float)hist[i] / 32768.0f;
    hs += em * logf(em + 1e-10f);
  }
  red[t] = hs;
  __syncthreads();
  for (int s2 = 128; s2 > 0; s2 >>= 1) {
    if (t < s2) red[t] += red[t + s2];
    __syncthreads();
  }
  if (t == 0) out_perp[0] = expf(-red[0]);
}

// ---------------------------------------------------------------------------
extern "C" void kernel_launch(void* const* d_in, const int* in_sizes, int n_in,
                              void* d_out, int out_size, void* d_ws, size_t ws_size,
                              hipStream_t stream) {
  const float* z   = (const float*)d_in[0];
  const float* emb = (const float*)d_in[1];
  float* out = (float*)d_out;

  float* out_zq   = out + ZQ_OFF;
  float* out_loss = out + LOSS_OFF;
  float* out_perp = out + PERP_OFF;
  float* out_enc  = out + ENC_OFF;
  float* out_idxf = out + IDX_OFF;

  // workspace layout
  int*   idx       = (int*)d_ws;                  // 32768
  int*   hist      = idx + NROWS;                 // 1024
  float* loss_part = (float*)(hist + NE);         // 1024
  float* znorm     = loss_part + NE;              // 32768
  float* enorm     = znorm + NROWS;               // 1024

  // zero one-hot output region (poisoned 0xAA before timing) and histogram
  hipMemsetAsync(out_enc, 0, (size_t)NROWS * NE * sizeof(float), stream);
  hipMemsetAsync(hist, 0, NE * sizeof(int), stream);

  znorm_kernel<<<NROWS / 256, 256, 0, stream>>>(z, znorm);
  enorm_kernel<<<NE / 256, 256, 0, stream>>>(emb, enorm);
  argmin_kernel<<<NROWS / BM, 256, 0, stream>>>(z, emb, enorm, znorm, idx);
  scatter_kernel<<<NROWS / 256, 256, 0, stream>>>(idx, out_enc, out_idxf, hist);
  gather_kernel<<<1024, 256, 0, stream>>>(z, emb, idx, out_zq, loss_part);
  finalize_kernel<<<1, 256, 0, stream>>>(loss_part, hist, out_loss, out_perp);
}